// Round 5
// baseline (340.606 us; speedup 1.0000x reference)
//
#include <hip/hip_runtime.h>
#include <hip/hip_bf16.h>
#include <hip/hip_cooperative_groups.h>

namespace cg = cooperative_groups;

#define N_NODES 50000
#define N_EDGES 800000
#define D 64
#define NB 1563       // fine buckets: dst>>5 -> 0..1562 (32 nodes/bucket)
#define BCAP 1024     // fixed slots per bucket region (max load ~600)
#define NSTRIP 3125   // N_NODES/16
#define MSTR 65       // mn row stride (u32): 65 mod 32 = 1 -> rows rotate banks
// fused cooperative grid
#define GRID_B 1024   // 4 blocks/CU, co-resident
#define GEMM_B 391    // 391 blocks * 4 waves * 2 strips = 3128 >= 3125
#define SCAT_B 633    // 1024 - 391
#define EPB 1264      // 633*1264 = 800112 >= 800000
// fallback (proven round-4 3-kernel path) params
#define CHUNK_E 2048
#define NSC 391
#define GEMM_BLKS 196
#define NWAVES 784
#define SPW 4

typedef __attribute__((ext_vector_type(8))) short short8v;   // 8 bf16 (4 VGPRs)
typedef __attribute__((ext_vector_type(4))) float float4v;   // 4 fp32 acc

// ---------- helpers ----------
__device__ __forceinline__ float b2f(unsigned short h) {
    return __uint_as_float(((unsigned)h) << 16);
}
__device__ __forceinline__ unsigned short f2b(float f) {
    __hip_bfloat16 t = __float2bfloat16(f);
    return *reinterpret_cast<unsigned short*>(&t);
}
__device__ __forceinline__ short f2bs(float f) { return (short)f2b(f); }
// monotonic float<->uint encoding: unsigned min == float min
__device__ __forceinline__ unsigned f2ord(float f) {
    unsigned u = __float_as_uint(f);
    return (u & 0x80000000u) ? ~u : (u | 0x80000000u);
}
__device__ __forceinline__ float ord2f(unsigned o) {
    return __uint_as_float((o & 0x80000000u) ? (o ^ 0x80000000u) : ~o);
}

// ---------- A(X)-fragment load helpers (strip w, lane m,q) ----------
__device__ __forceinline__ void loadA_bf16(const short* F, int w, int m, int q,
                                           short8v& A0, short8v& A1) {
    const short* fr = F + (w * 16 + m) * D + q * 8;
    A0 = *(const short8v*)fr;
    A1 = *(const short8v*)(fr + 32);
}
__device__ __forceinline__ void loadA_raw(const float* F, int w, int m, int q,
                                          float4 r[8]) {
    const float* fr = F + (w * 16 + m) * D + q * 8;
    r[0] = *(const float4*)(fr);      r[1] = *(const float4*)(fr + 4);
    r[2] = *(const float4*)(fr + 32); r[3] = *(const float4*)(fr + 36);
}
__device__ __forceinline__ void cvtA(const float4 r[8], short8v& A0, short8v& A1) {
    A0 = (short8v){f2bs(r[0].x), f2bs(r[0].y), f2bs(r[0].z), f2bs(r[0].w),
                   f2bs(r[1].x), f2bs(r[1].y), f2bs(r[1].z), f2bs(r[1].w)};
    A1 = (short8v){f2bs(r[2].x), f2bs(r[2].y), f2bs(r[2].z), f2bs(r[2].w),
                   f2bs(r[3].x), f2bs(r[3].y), f2bs(r[3].z), f2bs(r[3].w)};
}

// ================== FUSED cooperative kernel ==================
// Phase 0: block 0 builds W^T frags + bias_sum; blocks 1..7 zero c_cur;
//          block 8 zeros the phase-2 bucket cursor; every block computes
//          fp32mode/idx64 locally (128 B, L2-hot). grid.sync().
// Phase 1: blocks [0,GEMM_B): MFMA node transforms (swapped-operand ->
//          D[feat][node], uint2/float4 stores). blocks [GEMM_B,GRID_B):
//          two-phase bucket append (LDS histogram -> one reservation atomic
//          per non-empty (block,bucket) -> scatter). grid.sync().
// Phase 2: dynamic bucket grab via global cursor; per-bucket LDS-atomicMin
//          (stride-65 rows) + fused epilogue out = C - min.
__global__ __launch_bounds__(256, 4)
void fused(const void* __restrict__ featv, const void* __restrict__ srcv,
           const void* __restrict__ dstv, const void* __restrict__ Wtv,
           const void* __restrict__ btv, const void* __restrict__ Wpv,
           const void* __restrict__ bpv,
           unsigned* __restrict__ c_cur, unsigned* __restrict__ packed,
           unsigned short* __restrict__ T16,
           unsigned short* __restrict__ WTfrag, unsigned short* __restrict__ WPfrag,
           float* __restrict__ bias_sum, unsigned* __restrict__ cursor,
           void* __restrict__ outv) {
    __shared__ unsigned sh[32 * MSTR];                 // 2080 u32: hist (NB<=2080) / mn
    __shared__ unsigned sf[4];
    cg::grid_group grid = cg::this_grid();
    const int t = threadIdx.x;
    const int b = blockIdx.x;

    // local mode flags (every block; no global round-trip)
    if (t < 64) {
        const unsigned short* p = (const unsigned short*)featv;
        float x = b2f(p[2 * t]);
        float a = fabsf(x);
        bool insane = !(a <= 64.f) || (x != 0.f && a < 9.3132e-10f);
        unsigned long long m = __ballot(insane);
        if (t == 0) sf[0] = (__popcll(m) >= 8) ? 1u : 0u;
    } else if (t < 128) {
        const int* s32 = (const int*)srcv;
        int v = s32[2 * (t - 64) + 1];
        unsigned long long m = __ballot(v == 0);
        if (t == 64) sf[1] = (__popcll(m) >= 32) ? 1u : 0u;
    }
    __syncthreads();
    const unsigned fp32mode = sf[0];
    const unsigned idx64 = sf[1];

    // ---- phase 0 ----
    if (b == 0) {
#pragma unroll
        for (int i = 0; i < 16; ++i) {
            int e = i * 256 + t;                       // coalesced read
            int k = e >> 6, n = e & 63;
            float vt, vp;
            if (fp32mode) {
                vt = ((const float*)Wtv)[e];
                vp = ((const float*)Wpv)[e];
            } else {
                vt = b2f(((const unsigned short*)Wtv)[e]);
                vp = b2f(((const unsigned short*)Wpv)[e]);
            }
            WTfrag[n * 64 + k] = f2b(vt);              // Wfrag[n*64+k] = W[k][n]
            WPfrag[n * 64 + k] = f2b(vp);
        }
        if (t < 64) {
            if (fp32mode)
                bias_sum[t] = ((const float*)btv)[t] + ((const float*)bpv)[t];
            else
                bias_sum[t] = b2f(((const unsigned short*)btv)[t])
                            + b2f(((const unsigned short*)bpv)[t]);
        }
    } else if (b <= 7) {
        int i = (b - 1) * 256 + t;
        if (i < NB) c_cur[i] = 0;
    } else if (b == 8 && t == 0) {
        *cursor = 0;
    }
    grid.sync();

    // ---- phase 1 ----
    if (b < GEMM_B) {
        const int lane = t & 63, wid = t >> 6;
        const int m = lane & 15, q = lane >> 4;
        const short8v* BT = (const short8v*)WTfrag;    // idx = feat*8 + half*4 + q
        const short8v* BP = (const short8v*)WPfrag;
        short8v Wt0[4], Wt1[4], Wp0[4], Wp1[4];
        float4 bs4[4];
#pragma unroll
        for (int c = 0; c < 4; ++c) {
            const int col = 16 * c + m;
            Wt0[c] = BT[col * 8 + q];
            Wt1[c] = BT[col * 8 + 4 + q];
            Wp0[c] = BP[col * 8 + q];
            Wp1[c] = BP[col * 8 + 4 + q];
            bs4[c] = *(const float4*)(bias_sum + 16 * c + 4 * q);
        }
        float* Cf  = (float*)outv;
        unsigned short* Ch = (unsigned short*)outv;
#pragma unroll
        for (int si = 0; si < 2; ++si) {
            const int w = b * 8 + wid * 2 + si;        // strip
            if (w < NSTRIP) {
                short8v A0, A1;
                if (fp32mode) {
                    float4 raw[8];
                    loadA_raw((const float*)featv, w, m, q, raw);
                    cvtA(raw, A0, A1);
                } else {
                    loadA_bf16((const short*)featv, w, m, q, A0, A1);
                }
                const int node = w * 16 + m;
                unsigned short* Trow = T16 + node * D;
#pragma unroll
                for (int c = 0; c < 4; ++c) {
                    float4v accT = (float4v){0.f, 0.f, 0.f, 0.f};
                    float4v accP = (float4v){bs4[c].x, bs4[c].y, bs4[c].z, bs4[c].w};
                    // swapped operands: D = W^T x X^T -> D[feat][node]
                    accT = __builtin_amdgcn_mfma_f32_16x16x32_bf16(Wt0[c], A0, accT, 0, 0, 0);
                    accT = __builtin_amdgcn_mfma_f32_16x16x32_bf16(Wt1[c], A1, accT, 0, 0, 0);
                    accP = __builtin_amdgcn_mfma_f32_16x16x32_bf16(Wp0[c], A0, accP, 0, 0, 0);
                    accP = __builtin_amdgcn_mfma_f32_16x16x32_bf16(Wp1[c], A1, accP, 0, 0, 0);
                    const int foff = 16 * c + 4 * q;   // 4 consecutive feats
                    unsigned t0 = (unsigned)f2b(accT[0]) | ((unsigned)f2b(accT[1]) << 16);
                    unsigned t1 = (unsigned)f2b(accT[2]) | ((unsigned)f2b(accT[3]) << 16);
                    *(uint2*)(Trow + foff) = make_uint2(t0, t1);
                    if (fp32mode) {
                        *(float4*)(Cf + node * D + foff) =
                            make_float4(accT[0] + accP[0], accT[1] + accP[1],
                                        accT[2] + accP[2], accT[3] + accP[3]);
                    } else {
                        unsigned c0 = (unsigned)f2b(accT[0] + accP[0])
                                    | ((unsigned)f2b(accT[1] + accP[1]) << 16);
                        unsigned c1 = (unsigned)f2b(accT[2] + accP[2])
                                    | ((unsigned)f2b(accT[3] + accP[3]) << 16);
                        *(uint2*)(Ch + node * D + foff) = make_uint2(c0, c1);
                    }
                }
            }
        }
    } else {
        // ---- two-phase bucket append (proven round 2) ----
        const int base = (b - GEMM_B) * EPB;
        const int eend = min(base + EPB, N_EDGES);
        for (int i = t; i < NB; i += 256) sh[i] = 0;
        __syncthreads();
        unsigned pk[5];
#pragma unroll
        for (int j = 0; j < 5; ++j) {
            int e = base + j * 256 + t;
            unsigned p = 0xFFFFFFFFu;                  // sentinel
            if (e < eend) {
                int s, d;
                if (idx64) {
                    s = (int)((const long long*)srcv)[e];
                    d = (int)((const long long*)dstv)[e];
                } else {
                    s = ((const int*)srcv)[e];
                    d = ((const int*)dstv)[e];
                }
                s = min(max(s, 0), N_NODES - 1);
                d = min(max(d, 0), N_NODES - 1);
                if (s != d) {                          // self-loops seeded in phase 2
                    p = ((unsigned)d << 16) | (unsigned)s;
                    atomicAdd(&sh[d >> 5], 1u);
                }
            }
            pk[j] = p;
        }
        __syncthreads();
        // one reservation atomic per non-empty (block,bucket); sh becomes cursor
        for (int i = t; i < NB; i += 256) {
            unsigned c = sh[i];
            sh[i] = c ? atomicAdd(&c_cur[i], c) : 0u;
        }
        __syncthreads();
#pragma unroll
        for (int j = 0; j < 5; ++j) {
            unsigned p = pk[j];
            if (p != 0xFFFFFFFFu) {
                unsigned bkt = p >> 21;                // == dst>>5
                unsigned pos = atomicAdd(&sh[bkt], 1u);
                if (pos < BCAP)                        // overflow guard (never hits)
                    packed[bkt * BCAP + pos] = p;
            }
        }
    }
    grid.sync();

    // ---- phase 2: dynamic per-bucket LDS-atomic min + fused epilogue ----
    const int lane = t & 63, wv = t >> 6;              // 4 waves
    const int g = lane >> 3;                           // 8 edges per wave instr
    const int fh = (lane & 7) << 3;                    // short idx (8 shorts/lane)
    for (;;) {
        if (t == 0) sf[2] = atomicAdd(cursor, 1u);
        __syncthreads();
        const unsigned bb = sf[2];
        if (bb >= NB) break;
        const int node0 = (int)bb << 5;
        // seed with own-node T rows (covers self-loop edges)
        for (int sl = t; sl < 32 * 16; sl += 256) {
            const int row = sl >> 4;
            const int f4 = (sl & 15) << 2;
            unsigned* mp = &sh[row * MSTR + f4];
            if (node0 + row < N_NODES) {
                uint2 v = *(const uint2*)(T16 + (node0 + row) * D + f4);
                mp[0] = f2ord(b2f((unsigned short)v.x));
                mp[1] = f2ord(b2f((unsigned short)(v.x >> 16)));
                mp[2] = f2ord(b2f((unsigned short)v.y));
                mp[3] = f2ord(b2f((unsigned short)(v.y >> 16)));
            } else {
                mp[0] = mp[1] = mp[2] = mp[3] = 0xFFFFFFFFu;
            }
        }
        __syncthreads();
        const int cnt = min((int)c_cur[bb], BCAP);
        const unsigned* pb = packed + bb * BCAP;
        int i = wv * 8 + g;                            // 32 slots/block
        for (; i + 32 < cnt; i += 64) {                // 2 gathers in flight
            unsigned p0 = pb[i], p1 = pb[i + 32];
            uint4 v0 = *(const uint4*)(T16 + (int)(p0 & 0xFFFFu) * D + fh);
            uint4 v1 = *(const uint4*)(T16 + (int)(p1 & 0xFFFFu) * D + fh);
            unsigned* m0p = &sh[(int)((p0 >> 16) & 31u) * MSTR + fh];
            unsigned* m1p = &sh[(int)((p1 >> 16) & 31u) * MSTR + fh];
            atomicMin(m0p + 0, f2ord(b2f((unsigned short)v0.x)));
            atomicMin(m0p + 1, f2ord(b2f((unsigned short)(v0.x >> 16))));
            atomicMin(m0p + 2, f2ord(b2f((unsigned short)v0.y)));
            atomicMin(m0p + 3, f2ord(b2f((unsigned short)(v0.y >> 16))));
            atomicMin(m0p + 4, f2ord(b2f((unsigned short)v0.z)));
            atomicMin(m0p + 5, f2ord(b2f((unsigned short)(v0.z >> 16))));
            atomicMin(m0p + 6, f2ord(b2f((unsigned short)v0.w)));
            atomicMin(m0p + 7, f2ord(b2f((unsigned short)(v0.w >> 16))));
            atomicMin(m1p + 0, f2ord(b2f((unsigned short)v1.x)));
            atomicMin(m1p + 1, f2ord(b2f((unsigned short)(v1.x >> 16))));
            atomicMin(m1p + 2, f2ord(b2f((unsigned short)v1.y)));
            atomicMin(m1p + 3, f2ord(b2f((unsigned short)(v1.y >> 16))));
            atomicMin(m1p + 4, f2ord(b2f((unsigned short)v1.z)));
            atomicMin(m1p + 5, f2ord(b2f((unsigned short)(v1.z >> 16))));
            atomicMin(m1p + 6, f2ord(b2f((unsigned short)v1.w)));
            atomicMin(m1p + 7, f2ord(b2f((unsigned short)(v1.w >> 16))));
        }
        for (; i < cnt; i += 32) {
            unsigned p0 = pb[i];
            uint4 v0 = *(const uint4*)(T16 + (int)(p0 & 0xFFFFu) * D + fh);
            unsigned* m0p = &sh[(int)((p0 >> 16) & 31u) * MSTR + fh];
            atomicMin(m0p + 0, f2ord(b2f((unsigned short)v0.x)));
            atomicMin(m0p + 1, f2ord(b2f((unsigned short)(v0.x >> 16))));
            atomicMin(m0p + 2, f2ord(b2f((unsigned short)v0.y)));
            atomicMin(m0p + 3, f2ord(b2f((unsigned short)(v0.y >> 16))));
            atomicMin(m0p + 4, f2ord(b2f((unsigned short)v0.z)));
            atomicMin(m0p + 5, f2ord(b2f((unsigned short)(v0.z >> 16))));
            atomicMin(m0p + 6, f2ord(b2f((unsigned short)v0.w)));
            atomicMin(m0p + 7, f2ord(b2f((unsigned short)(v0.w >> 16))));
        }
        __syncthreads();
        // epilogue: out = C - min
        for (int sl = t; sl < 32 * 16; sl += 256) {
            const int row = sl >> 4;
            const int node = node0 + row;
            if (node >= N_NODES) continue;
            const int f4 = (sl & 15) << 2;
            const unsigned* mp = &sh[row * MSTR + f4];
            float m0 = ord2f(mp[0]), m1 = ord2f(mp[1]);
            float m2 = ord2f(mp[2]), m3 = ord2f(mp[3]);
            if (fp32mode) {
                float4* C = (float4*)((float*)outv + node * D + f4);
                float4 c = *C;
                *C = make_float4(c.x - m0, c.y - m1, c.z - m2, c.w - m3);
            } else {
                unsigned short* C = (unsigned short*)outv + node * D + f4;
                uint2 c = *(uint2*)C;
                unsigned lo = (unsigned)f2b(b2f((unsigned short)c.x) - m0)
                            | ((unsigned)f2b(b2f((unsigned short)(c.x >> 16)) - m1) << 16);
                unsigned hi = (unsigned)f2b(b2f((unsigned short)c.y) - m2)
                            | ((unsigned)f2b(b2f((unsigned short)(c.y >> 16)) - m3) << 16);
                *(uint2*)C = make_uint2(lo, hi);
            }
        }
        __syncthreads();                               // protect sh/sf reuse
    }
}

// ================== fallback: proven round-4 3-kernel path ==================
__global__ __launch_bounds__(256)
void setup(const void* __restrict__ featv, const void* __restrict__ srcv,
           const void* __restrict__ Wtv, const void* __restrict__ btv,
           const void* __restrict__ Wpv, const void* __restrict__ bpv,
           unsigned* __restrict__ flags, unsigned* __restrict__ c_cur,
           unsigned short* __restrict__ WTfrag, unsigned short* __restrict__ WPfrag,
           float* __restrict__ bias_sum) {
    __shared__ unsigned sf[2];
    const int t = threadIdx.x;
    if (t < 64) {
        const unsigned short* p = (const unsigned short*)featv;
        float x = b2f(p[2 * t]);
        float a = fabsf(x);
        bool insane = !(a <= 64.f) || (x != 0.f && a < 9.3132e-10f);
        unsigned long long m = __ballot(insane);
        if (t == 0) sf[0] = (__popcll(m) >= 8) ? 1u : 0u;
    } else if (t < 128) {
        const int* s32 = (const int*)srcv;
        int v = s32[2 * (t - 64) + 1];
        unsigned long long m = __ballot(v == 0);
        if (t == 64) sf[1] = (__popcll(m) >= 32) ? 1u : 0u;
    }
    __syncthreads();
    const unsigned fp32mode = sf[0];
    if (t < 2) flags[t] = sf[t];
    for (int i = t; i < NB; i += 256) c_cur[i] = 0;
#pragma unroll
    for (int i = 0; i < 16; ++i) {
        int e = i * 256 + t;
        int k = e >> 6, n = e & 63;
        float vt, vp;
        if (fp32mode) {
            vt = ((const float*)Wtv)[e];
            vp = ((const float*)Wpv)[e];
        } else {
            vt = b2f(((const unsigned short*)Wtv)[e]);
            vp = b2f(((const unsigned short*)Wpv)[e]);
        }
        WTfrag[n * 64 + k] = f2b(vt);
        WPfrag[n * 64 + k] = f2b(vp);
    }
    if (t < 64) {
        if (fp32mode)
            bias_sum[t] = ((const float*)btv)[t] + ((const float*)bpv)[t];
        else
            bias_sum[t] = b2f(((const unsigned short*)btv)[t])
                        + b2f(((const unsigned short*)bpv)[t]);
    }
}

__global__ __launch_bounds__(256)
void gemm_scatter(const void* __restrict__ featv,
                  const unsigned short* __restrict__ WTfrag,
                  const unsigned short* __restrict__ WPfrag,
                  const float* __restrict__ bias_sum,
                  const void* __restrict__ srcv, const void* __restrict__ dstv,
                  const unsigned* __restrict__ flags,
                  unsigned* __restrict__ c_cur, unsigned* __restrict__ packed,
                  unsigned short* __restrict__ T16, void* __restrict__ outv) {
    const unsigned fp32mode = flags[0];
    if (blockIdx.x < GEMM_BLKS) {
        const int lane = threadIdx.x & 63;
        const int wid  = threadIdx.x >> 6;
        const int wave = blockIdx.x * 4 + wid;
        const int m = lane & 15, q = lane >> 4;
        const short8v* BT = (const short8v*)WTfrag;
        const short8v* BP = (const short8v*)WPfrag;
        short8v Wt0[4], Wt1[4], Wp0[4], Wp1[4];
        float4 bs4[4];
#pragma unroll
        for (int c = 0; c < 4; ++c) {
            const int col = 16 * c + m;
            Wt0[c] = BT[col * 8 + q];
            Wt1[c] = BT[col * 8 + 4 + q];
            Wp0[c] = BP[col * 8 + q];
            Wp1[c] = BP[col * 8 + 4 + q];
            bs4[c] = *(const float4*)(bias_sum + 16 * c + 4 * q);
        }
        float* Cf  = (float*)outv;
        unsigned short* Ch = (unsigned short*)outv;
        const float* Ff = (const float*)featv;
        const short* Fh = (const short*)featv;
        short8v A0, A1;
        float4 raw[8];
        int w = wave;
        if (fp32mode) { loadA_raw(Ff, min(w, NSTRIP - 1), m, q, raw); cvtA(raw, A0, A1); }
        else          loadA_bf16(Fh, min(w, NSTRIP - 1), m, q, A0, A1);
#pragma unroll
        for (int s = 0; s < SPW; ++s) {
            const int wn = wave + (s + 1) * NWAVES;
            if (s + 1 < SPW) {
                if (fp32mode) loadA_raw(Ff, min(wn, NSTRIP - 1), m, q, raw);
                else          loadA_bf16(Fh, min(wn, NSTRIP - 1), m, q, A0, A1);
            }
            if (w < NSTRIP) {
                short8v Acur0, Acur1;
                if (s + 1 < SPW && !fp32mode) {
                    loadA_bf16(Fh, w, m, q, Acur0, Acur1);
                } else {
                    Acur0 = A0; Acur1 = A1;
                }
                const int node = w * 16 + m;
                unsigned short* Trow = T16 + node * D;
#pragma unroll
                for (int c = 0; c < 4; ++c) {
                    float4v accT = (float4v){0.f, 0.f, 0.f, 0.f};
                    float4v accP = (float4v){bs4[c].x, bs4[c].y, bs4[c].z, bs4[c].w};
                    accT = __builtin_amdgcn_mfma_f32_16x16x32_bf16(Wt0[c], Acur0, accT, 0, 0, 0);
                    accT = __builtin_amdgcn_mfma_f32_16x16x32_bf16(Wt1[c], Acur1, accT, 0, 0, 0);
                    accP = __builtin_amdgcn_mfma_f32_16x16x32_bf16(Wp0[c], Acur0, accP, 0, 0, 0);
                    accP = __builtin_amdgcn_mfma_f32_16x16x32_bf16(Wp1[c], Acur1, accP, 0, 0, 0);
                    const int foff = 16 * c + 4 * q;
                    unsigned t0 = (unsigned)f2b(accT[0]) | ((unsigned)f2b(accT[1]) << 16);
                    unsigned t1 = (unsigned)f2b(accT[2]) | ((unsigned)f2b(accT[3]) << 16);
                    *(uint2*)(Trow + foff) = make_uint2(t0, t1);
                    if (fp32mode) {
                        *(float4*)(Cf + node * D + foff) =
                            make_float4(accT[0] + accP[0], accT[1] + accP[1],
                                        accT[2] + accP[2], accT[3] + accP[3]);
                    } else {
                        unsigned c0 = (unsigned)f2b(accT[0] + accP[0])
                                    | ((unsigned)f2b(accT[1] + accP[1]) << 16);
                        unsigned c1 = (unsigned)f2b(accT[2] + accP[2])
                                    | ((unsigned)f2b(accT[3] + accP[3]) << 16);
                        *(uint2*)(Ch + node * D + foff) = make_uint2(c0, c1);
                    }
                }
            }
            w = wn;
            if (fp32mode && s + 1 < SPW) cvtA(raw, A0, A1);
        }
    } else {
        __shared__ unsigned h[NB];
        const int t = threadIdx.x;
        for (int i = t; i < NB; i += 256) h[i] = 0;
        __syncthreads();
        const unsigned idx64 = flags[1];
        const int base = (blockIdx.x - GEMM_BLKS) * CHUNK_E;
        unsigned pk[CHUNK_E / 256];
#pragma unroll
        for (int j = 0; j < CHUNK_E / 256; ++j) {
            int e = base + j * 256 + t;
            unsigned p = 0xFFFFFFFFu;
            if (e < N_EDGES) {
                int s, d;
                if (idx64) {
                    s = (int)((const long long*)srcv)[e];
                    d = (int)((const long long*)dstv)[e];
                } else {
                    s = ((const int*)srcv)[e];
                    d = ((const int*)dstv)[e];
                }
                s = min(max(s, 0), N_NODES - 1);
                d = min(max(d, 0), N_NODES - 1);
                if (s != d) {
                    p = ((unsigned)d << 16) | (unsigned)s;
                    atomicAdd(&h[d >> 5], 1u);
                }
            }
            pk[j] = p;
        }
        __syncthreads();
        for (int i = t; i < NB; i += 256) {
            unsigned c = h[i];
            h[i] = c ? atomicAdd(&c_cur[i], c) : 0u;
        }
        __syncthreads();
#pragma unroll
        for (int j = 0; j < CHUNK_E / 256; ++j) {
            unsigned p = pk[j];
            if (p != 0xFFFFFFFFu) {
                unsigned bkt = p >> 21;
                unsigned pos = atomicAdd(&h[bkt], 1u);
                if (pos < BCAP)
                    packed[bkt * BCAP + pos] = p;
            }
        }
    }
}

__global__ __launch_bounds__(256, 8)
void bucket_min(const unsigned* __restrict__ c_cur, const unsigned* __restrict__ packed,
                const unsigned short* __restrict__ T16, const unsigned* __restrict__ flags,
                void* __restrict__ outv) {
    __shared__ unsigned mn[32 * MSTR];
    const unsigned fp32mode = flags[0];
    const int t = threadIdx.x;
    const int b = blockIdx.x;
    const int node0 = b << 5;
    for (int sl = t; sl < 32 * 16; sl += 256) {
        const int row = sl >> 4;
        const int f4 = (sl & 15) << 2;
        unsigned* mp = &mn[row * MSTR + f4];
        if (node0 + row < N_NODES) {
            uint2 v = *(const uint2*)(T16 + (node0 + row) * D + f4);
            mp[0] = f2ord(b2f((unsigned short)v.x));
            mp[1] = f2ord(b2f((unsigned short)(v.x >> 16)));
            mp[2] = f2ord(b2f((unsigned short)v.y));
            mp[3] = f2ord(b2f((unsigned short)(v.y >> 16)));
        } else {
            mp[0] = mp[1] = mp[2] = mp[3] = 0xFFFFFFFFu;
        }
    }
    __syncthreads();
    const int cnt = min((int)c_cur[b], BCAP);
    const unsigned* pb = packed + b * BCAP;
    const int lane = t & 63, wv = t >> 6;
    const int g = lane >> 3;
    const int fh = (lane & 7) << 3;
    int i = wv * 8 + g;
    for (; i + 32 < cnt; i += 64) {
        unsigned p0 = pb[i], p1 = pb[i + 32];
        uint4 v0 = *(const uint4*)(T16 + (int)(p0 & 0xFFFFu) * D + fh);
        uint4 v1 = *(const uint4*)(T16 + (int)(p1 & 0xFFFFu) * D + fh);
        unsigned* m0p = &mn[(int)((p0 >> 16) & 31u) * MSTR + fh];
        unsigned* m1p = &mn[(int)((p1 >> 16) & 31u) * MSTR + fh];
        atomicMin(m0p + 0, f2ord(b2f((unsigned short)v0.x)));
        atomicMin(m0p + 1, f2ord(b2f((unsigned short)(v0.x >> 16))));
        atomicMin(m0p + 2, f2ord(b2f((unsigned short)v0.y)));
        atomicMin(m0p + 3, f2ord(b2f((unsigned short)(v0.y >> 16))));
        atomicMin(m0p + 4, f2ord(b2f((unsigned short)v0.z)));
        atomicMin(m0p + 5, f2ord(b2f((unsigned short)(v0.z >> 16))));
        atomicMin(m0p + 6, f2ord(b2f((unsigned short)v0.w)));
        atomicMin(m0p + 7, f2ord(b2f((unsigned short)(v0.w >> 16))));
        atomicMin(m1p + 0, f2ord(b2f((unsigned short)v1.x)));
        atomicMin(m1p + 1, f2ord(b2f((unsigned short)(v1.x >> 16))));
        atomicMin(m1p + 2, f2ord(b2f((unsigned short)v1.y)));
        atomicMin(m1p + 3, f2ord(b2f((unsigned short)(v1.y >> 16))));
        atomicMin(m1p + 4, f2ord(b2f((unsigned short)v1.z)));
        atomicMin(m1p + 5, f2ord(b2f((unsigned short)(v1.z >> 16))));
        atomicMin(m1p + 6, f2ord(b2f((unsigned short)v1.w)));
        atomicMin(m1p + 7, f2ord(b2f((unsigned short)(v1.w >> 16))));
    }
    for (; i < cnt; i += 32) {
        unsigned p0 = pb[i];
        uint4 v0 = *(const uint4*)(T16 + (int)(p0 & 0xFFFFu) * D + fh);
        unsigned* m0p = &mn[(int)((p0 >> 16) & 31u) * MSTR + fh];
        atomicMin(m0p + 0, f2ord(b2f((unsigned short)v0.x)));
        atomicMin(m0p + 1, f2ord(b2f((unsigned short)(v0.x >> 16))));
        atomicMin(m0p + 2, f2ord(b2f((unsigned short)v0.y)));
        atomicMin(m0p + 3, f2ord(b2f((unsigned short)(v0.y >> 16))));
        atomicMin(m0p + 4, f2ord(b2f((unsigned short)v0.z)));
        atomicMin(m0p + 5, f2ord(b2f((unsigned short)(v0.z >> 16))));
        atomicMin(m0p + 6, f2ord(b2f((unsigned short)v0.w)));
        atomicMin(m0p + 7, f2ord(b2f((unsigned short)(v0.w >> 16))));
    }
    __syncthreads();
    for (int sl = t; sl < 32 * 16; sl += 256) {
        const int row = sl >> 4;
        const int node = node0 + row;
        if (node >= N_NODES) continue;
        const int f4 = (sl & 15) << 2;
        const unsigned* mp = &mn[row * MSTR + f4];
        float m0 = ord2f(mp[0]), m1 = ord2f(mp[1]);
        float m2 = ord2f(mp[2]), m3 = ord2f(mp[3]);
        if (fp32mode) {
            float4* C = (float4*)((float*)outv + node * D + f4);
            float4 c = *C;
            *C = make_float4(c.x - m0, c.y - m1, c.z - m2, c.w - m3);
        } else {
            unsigned short* C = (unsigned short*)outv + node * D + f4;
            uint2 c = *(uint2*)C;
            unsigned lo = (unsigned)f2b(b2f((unsigned short)c.x) - m0)
                        | ((unsigned)f2b(b2f((unsigned short)(c.x >> 16)) - m1) << 16);
            unsigned hi = (unsigned)f2b(b2f((unsigned short)c.y) - m2)
                        | ((unsigned)f2b(b2f((unsigned short)(c.y >> 16)) - m3) << 16);
            *(uint2*)C = make_uint2(lo, hi);
        }
    }
}

extern "C" void kernel_launch(void* const* d_in, const int* in_sizes, int n_in,
                              void* d_out, int out_size, void* d_ws, size_t ws_size,
                              hipStream_t stream) {
    // ws layout (~12.8 MB used; ws is ~256 MB):
    char* p = (char*)d_ws;
    unsigned*       flags    = (unsigned*)p;                     // 256 B (fallback only)
    unsigned*       c_cur    = (unsigned*)(p + 256);             // 1563*4 -> pad 8192
    unsigned*       packed   = (unsigned*)(p + 8448);            // 1563*1024*4 = 6.40 MB
    unsigned short* T16      = (unsigned short*)(p + 8448 + 6402048);   // 6.4 MB
    unsigned short* WTfrag   = (unsigned short*)(p + 8448 + 6402048 + 6400000);        // 8 KB
    unsigned short* WPfrag   = (unsigned short*)(p + 8448 + 6402048 + 6400000 + 8192); // 8 KB
    float*          bias_sum = (float*)(p + 8448 + 6402048 + 6400000 + 16384);         // 256 B
    unsigned*       cursor   = (unsigned*)(p + 8448 + 6402048 + 6400000 + 16640);      // 4 B

    const void* featv = d_in[0];
    const void* srcv  = d_in[1];
    const void* dstv  = d_in[2];
    const void* Wtv   = d_in[3];
    const void* btv   = d_in[4];
    const void* Wpv   = d_in[5];
    const void* bpv   = d_in[6];
    void* outv = d_out;

    void* kargs[] = { (void*)&featv, (void*)&srcv, (void*)&dstv, (void*)&Wtv,
                      (void*)&btv, (void*)&Wpv, (void*)&bpv,
                      (void*)&c_cur, (void*)&packed, (void*)&T16,
                      (void*)&WTfrag, (void*)&WPfrag, (void*)&bias_sum,
                      (void*)&cursor, (void*)&outv };
    hipError_t err = hipLaunchCooperativeKernel((const void*)fused, dim3(GRID_B),
                                                dim3(256), kargs, 0, stream);
    if (err != hipSuccess) {
        // fallback: proven round-4 3-kernel path
        setup<<<1, 256, 0, stream>>>(featv, srcv, Wtv, btv, Wpv, bpv,
                                     flags, c_cur, WTfrag, WPfrag, bias_sum);
        gemm_scatter<<<GEMM_BLKS + NSC, 256, 0, stream>>>(featv, WTfrag, WPfrag, bias_sum,
                                                          srcv, dstv, flags,
                                                          c_cur, packed, T16, outv);
        bucket_min<<<NB, 256, 0, stream>>>(c_cur, packed, T16, flags, outv);
    }
}

// Round 6
// 113.363 us; speedup vs baseline: 3.0046x; 3.0046x over previous
//
#include <hip/hip_runtime.h>
#include <hip/hip_bf16.h>

#define N_NODES 50000
#define N_EDGES 800000
#define D 64
#define NB 1563       // fine buckets: dst>>5 -> 0..1562 (32 nodes/bucket)
#define BCAP 1024     // fixed slots per bucket region (max load ~600)
#define CHUNK_E 4096  // edges per scatter block (halves reservation atomics)
#define NSC 196       // ceil(800000/4096)
#define NSTRIP 3125   // N_NODES/16
#define GEMM_BLKS 196 // 196*4 waves * 4 strips = 3136 >= NSTRIP
#define NWAVES 784    // gemm waves
#define SPW 4         // strips per wave
#define MSTR 65       // mn row stride (u32): rows rotate banks
#define WLSTR 72      // W^T LDS row stride (u16): 144 B rows -> 16B-aligned b128 reads
#define NRES 7        // reservation rounds: 7*256 >= NB

typedef __attribute__((ext_vector_type(8))) short short8v;   // 8 bf16 (4 VGPRs)
typedef __attribute__((ext_vector_type(4))) float float4v;   // 4 fp32 acc

// ---------- helpers ----------
__device__ __forceinline__ float b2f(unsigned short h) {
    return __uint_as_float(((unsigned)h) << 16);
}
__device__ __forceinline__ unsigned short f2b(float f) {
    __hip_bfloat16 t = __float2bfloat16(f);
    return *reinterpret_cast<unsigned short*>(&t);
}
// monotonic float<->uint encoding: unsigned min == float min
__device__ __forceinline__ unsigned f2ord(float f) {
    unsigned u = __float_as_uint(f);
    return (u & 0x80000000u) ? ~u : (u | 0x80000000u);
}
__device__ __forceinline__ float ord2f(unsigned o) {
    return __uint_as_float((o & 0x80000000u) ? (o ^ 0x80000000u) : ~o);
}

// ---------- kernel 1: fused [MFMA node transforms ∥ bucket append] ----------
// No setup kernel: every block computes its mode flags locally (128 B, L2-hot);
// GEMM blocks self-stage W^T into LDS (coalesced read, stride-72 transposed
// rows -> 16B-aligned ds_read_b128 fragment loads); scatter blocks rely only on
// c_cur zeroed by the preceding 6 KB hipMemsetAsync.
// gemm blocks [0, GEMM_BLKS): 4 strips/wave, swapped-operand MFMA (verified):
//   mfma(Wfrag, Xfrag) -> D[feat][node]: lane m owns node w*16+m, regs hold 4
//   consecutive feats -> uint2/float4 stores.
// blocks [GEMM_BLKS, +NSC): two-phase append (dst<<16|src) into fixed-stride
//   bucket regions; reservation atomics issued back-to-back for vmcnt ILP.
__global__ __launch_bounds__(256)
void gemm_scatter(const void* __restrict__ featv,
                  const void* __restrict__ srcv, const void* __restrict__ dstv,
                  const void* __restrict__ Wtv, const void* __restrict__ btv,
                  const void* __restrict__ Wpv, const void* __restrict__ bpv,
                  unsigned* __restrict__ c_cur, unsigned* __restrict__ packed,
                  unsigned short* __restrict__ T16, void* __restrict__ outv) {
    __shared__ __align__(16) unsigned short wt_l[64 * WLSTR];  // 9.2 KB
    __shared__ __align__(16) unsigned short wp_l[64 * WLSTR];  // 9.2 KB
    __shared__ __align__(16) float bias_l[64];
    __shared__ unsigned h[NB];                                 // 6.3 KB
    __shared__ unsigned sf[2];
    const int t = threadIdx.x;

    // local mode flags (every block; no global round-trip)
    if (t < 64) {
        const unsigned short* p = (const unsigned short*)featv;
        float x = b2f(p[2 * t]);
        float a = fabsf(x);
        bool insane = !(a <= 64.f) || (x != 0.f && a < 9.3132e-10f);
        unsigned long long mm = __ballot(insane);
        if (t == 0) sf[0] = (__popcll(mm) >= 8) ? 1u : 0u;
    } else if (t < 128) {
        const int* s32 = (const int*)srcv;
        int v = s32[2 * (t - 64) + 1];
        unsigned long long mm = __ballot(v == 0);
        if (t == 64) sf[1] = (__popcll(mm) >= 32) ? 1u : 0u;
    }
    __syncthreads();
    const unsigned fp32mode = sf[0];
    const unsigned idx64 = sf[1];

    if (blockIdx.x < GEMM_BLKS) {
        // ---- self-stage W^T into LDS: wt_l[n*WLSTR + k] = W[k][n] ----
        if (fp32mode) {
#pragma unroll
            for (int i = 0; i < 16; ++i) {
                int e = i * 256 + t;                   // coalesced read
                int k = e >> 6, n = e & 63;
                wt_l[n * WLSTR + k] = f2b(((const float*)Wtv)[e]);
                wp_l[n * WLSTR + k] = f2b(((const float*)Wpv)[e]);
            }
        } else {
#pragma unroll
            for (int i = 0; i < 16; ++i) {
                int e = i * 256 + t;
                int k = e >> 6, n = e & 63;
                wt_l[n * WLSTR + k] = ((const unsigned short*)Wtv)[e];
                wp_l[n * WLSTR + k] = ((const unsigned short*)Wpv)[e];
            }
        }
        if (t < 64) {
            float bt_, bp_;
            if (fp32mode) {
                bt_ = ((const float*)btv)[t];
                bp_ = ((const float*)bpv)[t];
            } else {
                bt_ = b2f(((const unsigned short*)btv)[t]);
                bp_ = b2f(((const unsigned short*)bpv)[t]);
            }
            bias_l[t] = bt_ + bp_;
        }
        __syncthreads();

        const int lane = t & 63, wid = t >> 6;
        const int wave = blockIdx.x * 4 + wid;         // 0..783
        const int m = lane & 15, q = lane >> 4;
        // fragment loads: 16B-aligned (col*144 + 16q), ds_read_b128
        short8v Wt0[4], Wt1[4], Wp0[4], Wp1[4];
        float4 bs4[4];
#pragma unroll
        for (int c = 0; c < 4; ++c) {
            const int col = 16 * c + m;
            Wt0[c] = *(const short8v*)&wt_l[col * WLSTR + q * 8];
            Wt1[c] = *(const short8v*)&wt_l[col * WLSTR + 32 + q * 8];
            Wp0[c] = *(const short8v*)&wp_l[col * WLSTR + q * 8];
            Wp1[c] = *(const short8v*)&wp_l[col * WLSTR + 32 + q * 8];
            bs4[c] = *(const float4*)&bias_l[16 * c + 4 * q];
        }

        float* Cf  = (float*)outv;
        unsigned short* Ch = (unsigned short*)outv;
        const float* Ff = (const float*)featv;
        const short* Fh = (const short*)featv;

        // software pipeline: load A for strip s+1 while computing strip s
        short8v A0, A1;
        float4 raw[8];
        int w = wave;                                  // strip s=0
        {
            int wc = min(w, NSTRIP - 1);
            const short* fr = Fh + (wc * 16 + m) * D + q * 8;
            const float* frf = Ff + (wc * 16 + m) * D + q * 8;
            if (fp32mode) {
                raw[0] = *(const float4*)(frf);      raw[1] = *(const float4*)(frf + 4);
                raw[2] = *(const float4*)(frf + 32); raw[3] = *(const float4*)(frf + 36);
                A0 = (short8v){(short)f2b(raw[0].x), (short)f2b(raw[0].y), (short)f2b(raw[0].z), (short)f2b(raw[0].w),
                               (short)f2b(raw[1].x), (short)f2b(raw[1].y), (short)f2b(raw[1].z), (short)f2b(raw[1].w)};
                A1 = (short8v){(short)f2b(raw[2].x), (short)f2b(raw[2].y), (short)f2b(raw[2].z), (short)f2b(raw[2].w),
                               (short)f2b(raw[3].x), (short)f2b(raw[3].y), (short)f2b(raw[3].z), (short)f2b(raw[3].w)};
            } else {
                A0 = *(const short8v*)fr;
                A1 = *(const short8v*)(fr + 32);
            }
        }

#pragma unroll
        for (int s = 0; s < SPW; ++s) {
            const int wn = wave + (s + 1) * NWAVES;    // next strip (prefetch)
            if (s + 1 < SPW) {
                int wc = min(wn, NSTRIP - 1);
                if (fp32mode) {
                    const float* frf = Ff + (wc * 16 + m) * D + q * 8;
                    raw[0] = *(const float4*)(frf);      raw[1] = *(const float4*)(frf + 4);
                    raw[2] = *(const float4*)(frf + 32); raw[3] = *(const float4*)(frf + 36);
                } else {
                    const short* fr = Fh + (wc * 16 + m) * D + q * 8;
                    A0 = *(const short8v*)fr;
                    A1 = *(const short8v*)(fr + 32);
                }
            }
            if (w < NSTRIP) {
                short8v Acur0, Acur1;
                if (s + 1 < SPW && !fp32mode) {
                    // A0/A1 hold NEXT; reload current cheaply from L1/L2
                    const short* fr = Fh + (w * 16 + m) * D + q * 8;
                    Acur0 = *(const short8v*)fr;
                    Acur1 = *(const short8v*)(fr + 32);
                } else {
                    Acur0 = A0; Acur1 = A1;            // fp32: A holds current
                }
                const int node = w * 16 + m;
                unsigned short* Trow = T16 + node * D;
#pragma unroll
                for (int c = 0; c < 4; ++c) {
                    float4v accT = (float4v){0.f, 0.f, 0.f, 0.f};
                    float4v accP = (float4v){bs4[c].x, bs4[c].y, bs4[c].z, bs4[c].w};
                    // swapped operands: D = W^T x X^T -> D[feat][node]
                    accT = __builtin_amdgcn_mfma_f32_16x16x32_bf16(Wt0[c], Acur0, accT, 0, 0, 0);
                    accT = __builtin_amdgcn_mfma_f32_16x16x32_bf16(Wt1[c], Acur1, accT, 0, 0, 0);
                    accP = __builtin_amdgcn_mfma_f32_16x16x32_bf16(Wp0[c], Acur0, accP, 0, 0, 0);
                    accP = __builtin_amdgcn_mfma_f32_16x16x32_bf16(Wp1[c], Acur1, accP, 0, 0, 0);
                    // D layout: col(lane&15)=node-in-strip, row(q*4+r)=feat
                    const int foff = 16 * c + 4 * q;   // 4 consecutive feats
                    unsigned t0 = (unsigned)f2b(accT[0]) | ((unsigned)f2b(accT[1]) << 16);
                    unsigned t1 = (unsigned)f2b(accT[2]) | ((unsigned)f2b(accT[3]) << 16);
                    *(uint2*)(Trow + foff) = make_uint2(t0, t1);
                    if (fp32mode) {
                        *(float4*)(Cf + node * D + foff) =
                            make_float4(accT[0] + accP[0], accT[1] + accP[1],
                                        accT[2] + accP[2], accT[3] + accP[3]);
                    } else {
                        unsigned c0 = (unsigned)f2b(accT[0] + accP[0])
                                    | ((unsigned)f2b(accT[1] + accP[1]) << 16);
                        unsigned c1 = (unsigned)f2b(accT[2] + accP[2])
                                    | ((unsigned)f2b(accT[3] + accP[3]) << 16);
                        *(uint2*)(Ch + node * D + foff) = make_uint2(c0, c1);
                    }
                }
            }
            w = wn;
            if (fp32mode && s + 1 < SPW) {
                A0 = (short8v){(short)f2b(raw[0].x), (short)f2b(raw[0].y), (short)f2b(raw[0].z), (short)f2b(raw[0].w),
                               (short)f2b(raw[1].x), (short)f2b(raw[1].y), (short)f2b(raw[1].z), (short)f2b(raw[1].w)};
                A1 = (short8v){(short)f2b(raw[2].x), (short)f2b(raw[2].y), (short)f2b(raw[2].z), (short)f2b(raw[2].w),
                               (short)f2b(raw[3].x), (short)f2b(raw[3].y), (short)f2b(raw[3].z), (short)f2b(raw[3].w)};
            }
        }
    } else {
        // ---- two-phase bucket append (proven round 2/4) ----
        for (int i = t; i < NB; i += 256) h[i] = 0;
        __syncthreads();
        const int base = (blockIdx.x - GEMM_BLKS) * CHUNK_E;
        unsigned pk[CHUNK_E / 256];
#pragma unroll
        for (int j = 0; j < CHUNK_E / 256; ++j) {
            int e = base + j * 256 + t;
            unsigned p = 0xFFFFFFFFu;                  // sentinel
            if (e < N_EDGES) {
                int s, d;
                if (idx64) {
                    s = (int)((const long long*)srcv)[e];
                    d = (int)((const long long*)dstv)[e];
                } else {
                    s = ((const int*)srcv)[e];
                    d = ((const int*)dstv)[e];
                }
                s = min(max(s, 0), N_NODES - 1);
                d = min(max(d, 0), N_NODES - 1);
                if (s != d) {                          // self-loops seeded in k2
                    p = ((unsigned)d << 16) | (unsigned)s;
                    atomicAdd(&h[d >> 5], 1u);
                }
            }
            pk[j] = p;
        }
        __syncthreads();
        // reservation: load all counts, issue atomics back-to-back (vmcnt ILP),
        // then write cursors back. One atomic per non-empty (block,bucket).
        {
            unsigned cc[NRES], off[NRES];
#pragma unroll
            for (int r = 0; r < NRES; ++r) {
                int i = r * 256 + t;
                cc[r] = (i < NB) ? h[i] : 0u;
            }
#pragma unroll
            for (int r = 0; r < NRES; ++r) {
                int i = r * 256 + t;
                off[r] = (i < NB && cc[r]) ? atomicAdd(&c_cur[i], cc[r]) : 0u;
            }
            __syncthreads();
#pragma unroll
            for (int r = 0; r < NRES; ++r) {
                int i = r * 256 + t;
                if (i < NB) h[i] = off[r];
            }
        }
        __syncthreads();
#pragma unroll
        for (int j = 0; j < CHUNK_E / 256; ++j) {
            unsigned p = pk[j];
            if (p != 0xFFFFFFFFu) {
                unsigned bkt = p >> 21;                // == dst>>5
                unsigned pos = atomicAdd(&h[bkt], 1u);
                if (pos < BCAP)                        // overflow guard (never hits)
                    packed[bkt * BCAP + pos] = p;
            }
        }
    }
}

// ---------- kernel 2: per-bucket LDS-atomic min + fused epilogue ----------
// One block per bucket of 32 nodes. mn[32] rows of 64 ord-u32 minima in LDS at
// row stride 65 (rows rotate the bank set). Seeded with each node's own T row
// (covers self-loops). uint4 gathers: 8 lanes x 8 shorts per T row, 8 edges
// per wave instruction, 2 gathers in flight. fp32mode self-computed.
// 256 thr, launch_bounds(256,8): all 1563 blocks co-resident (8 blocks/CU).
__global__ __launch_bounds__(256, 8)
void bucket_min(const unsigned* __restrict__ c_cur, const unsigned* __restrict__ packed,
                const unsigned short* __restrict__ T16, const void* __restrict__ featv,
                void* __restrict__ outv) {
    __shared__ unsigned mn[32 * MSTR];                 // 8.3 KB
    __shared__ unsigned sf0;
    const int t = threadIdx.x;
    const int b = blockIdx.x;
    const int node0 = b << 5;
    if (t < 64) {
        const unsigned short* p = (const unsigned short*)featv;
        float x = b2f(p[2 * t]);
        float a = fabsf(x);
        bool insane = !(a <= 64.f) || (x != 0.f && a < 9.3132e-10f);
        unsigned long long mm = __ballot(insane);
        if (t == 0) sf0 = (__popcll(mm) >= 8) ? 1u : 0u;
    }
    // seed with own-node T rows (coalesced 4 KB; covers self-loop edges)
    for (int sl = t; sl < 32 * 16; sl += 256) {
        const int row = sl >> 4;
        const int f4 = (sl & 15) << 2;
        unsigned* mp = &mn[row * MSTR + f4];
        if (node0 + row < N_NODES) {
            uint2 v = *(const uint2*)(T16 + (node0 + row) * D + f4);
            mp[0] = f2ord(b2f((unsigned short)v.x));
            mp[1] = f2ord(b2f((unsigned short)(v.x >> 16)));
            mp[2] = f2ord(b2f((unsigned short)v.y));
            mp[3] = f2ord(b2f((unsigned short)(v.y >> 16)));
        } else {
            mp[0] = mp[1] = mp[2] = mp[3] = 0xFFFFFFFFu;
        }
    }
    __syncthreads();
    const unsigned fp32mode = sf0;
    const int cnt = min((int)c_cur[b], BCAP);
    const unsigned* pb = packed + b * BCAP;
    const int lane = t & 63, wv = t >> 6;              // 4 waves
    const int g = lane >> 3;                           // 8 edges per wave instr
    const int fh = (lane & 7) << 3;                    // short/u32 idx (8/lane)
    int i = wv * 8 + g;                                // 32 slots/block
    for (; i + 32 < cnt; i += 64) {                    // 2 gathers in flight
        unsigned p0 = pb[i], p1 = pb[i + 32];
        uint4 v0 = *(const uint4*)(T16 + (int)(p0 & 0xFFFFu) * D + fh);
        uint4 v1 = *(const uint4*)(T16 + (int)(p1 & 0xFFFFu) * D + fh);
        unsigned* m0p = &mn[(int)((p0 >> 16) & 31u) * MSTR + fh];
        unsigned* m1p = &mn[(int)((p1 >> 16) & 31u) * MSTR + fh];
        atomicMin(m0p + 0, f2ord(b2f((unsigned short)v0.x)));
        atomicMin(m0p + 1, f2ord(b2f((unsigned short)(v0.x >> 16))));
        atomicMin(m0p + 2, f2ord(b2f((unsigned short)v0.y)));
        atomicMin(m0p + 3, f2ord(b2f((unsigned short)(v0.y >> 16))));
        atomicMin(m0p + 4, f2ord(b2f((unsigned short)v0.z)));
        atomicMin(m0p + 5, f2ord(b2f((unsigned short)(v0.z >> 16))));
        atomicMin(m0p + 6, f2ord(b2f((unsigned short)v0.w)));
        atomicMin(m0p + 7, f2ord(b2f((unsigned short)(v0.w >> 16))));
        atomicMin(m1p + 0, f2ord(b2f((unsigned short)v1.x)));
        atomicMin(m1p + 1, f2ord(b2f((unsigned short)(v1.x >> 16))));
        atomicMin(m1p + 2, f2ord(b2f((unsigned short)v1.y)));
        atomicMin(m1p + 3, f2ord(b2f((unsigned short)(v1.y >> 16))));
        atomicMin(m1p + 4, f2ord(b2f((unsigned short)v1.z)));
        atomicMin(m1p + 5, f2ord(b2f((unsigned short)(v1.z >> 16))));
        atomicMin(m1p + 6, f2ord(b2f((unsigned short)v1.w)));
        atomicMin(m1p + 7, f2ord(b2f((unsigned short)(v1.w >> 16))));
    }
    for (; i < cnt; i += 32) {
        unsigned p0 = pb[i];
        uint4 v0 = *(const uint4*)(T16 + (int)(p0 & 0xFFFFu) * D + fh);
        unsigned* m0p = &mn[(int)((p0 >> 16) & 31u) * MSTR + fh];
        atomicMin(m0p + 0, f2ord(b2f((unsigned short)v0.x)));
        atomicMin(m0p + 1, f2ord(b2f((unsigned short)(v0.x >> 16))));
        atomicMin(m0p + 2, f2ord(b2f((unsigned short)v0.y)));
        atomicMin(m0p + 3, f2ord(b2f((unsigned short)(v0.y >> 16))));
        atomicMin(m0p + 4, f2ord(b2f((unsigned short)v0.z)));
        atomicMin(m0p + 5, f2ord(b2f((unsigned short)(v0.z >> 16))));
        atomicMin(m0p + 6, f2ord(b2f((unsigned short)v0.w)));
        atomicMin(m0p + 7, f2ord(b2f((unsigned short)(v0.w >> 16))));
    }
    __syncthreads();
    // epilogue: out = C - min for the bucket's 32 nodes
    for (int sl = t; sl < 32 * 16; sl += 256) {
        const int row = sl >> 4;
        const int node = node0 + row;
        if (node >= N_NODES) continue;
        const int f4 = (sl & 15) << 2;
        const unsigned* mp = &mn[row * MSTR + f4];
        float m0 = ord2f(mp[0]), m1 = ord2f(mp[1]);
        float m2 = ord2f(mp[2]), m3 = ord2f(mp[3]);
        if (fp32mode) {
            float4* C = (float4*)((float*)outv + node * D + f4);
            float4 c = *C;
            *C = make_float4(c.x - m0, c.y - m1, c.z - m2, c.w - m3);
        } else {
            unsigned short* C = (unsigned short*)outv + node * D + f4;
            uint2 c = *(uint2*)C;
            unsigned lo = (unsigned)f2b(b2f((unsigned short)c.x) - m0)
                        | ((unsigned)f2b(b2f((unsigned short)(c.x >> 16)) - m1) << 16);
            unsigned hi = (unsigned)f2b(b2f((unsigned short)c.y) - m2)
                        | ((unsigned)f2b(b2f((unsigned short)(c.y >> 16)) - m3) << 16);
            *(uint2*)C = make_uint2(lo, hi);
        }
    }
}

// fallback zeroing kernel (if hipMemsetAsync is rejected by capture)
__global__ __launch_bounds__(256)
void zero_ccur(unsigned* __restrict__ c_cur) {
    int i = blockIdx.x * 256 + threadIdx.x;
    if (i < NB) c_cur[i] = 0;
}

extern "C" void kernel_launch(void* const* d_in, const int* in_sizes, int n_in,
                              void* d_out, int out_size, void* d_ws, size_t ws_size,
                              hipStream_t stream) {
    // ws layout (~12.8 MB used; ws is ~256 MB):
    char* p = (char*)d_ws;
    unsigned*       c_cur  = (unsigned*)p;                       // 1563*4 -> pad 8192
    unsigned*       packed = (unsigned*)(p + 8192);              // 1563*1024*4 = 6.40 MB
    unsigned short* T16    = (unsigned short*)(p + 8192 + 6402048);  // 6.4 MB (16B-aligned)

    hipError_t e = hipMemsetAsync(c_cur, 0, NB * sizeof(unsigned), stream);
    if (e != hipSuccess)
        zero_ccur<<<(NB + 255) / 256, 256, 0, stream>>>(c_cur);

    gemm_scatter<<<GEMM_BLKS + NSC, 256, 0, stream>>>(d_in[0], d_in[1], d_in[2],
                                                      d_in[3], d_in[4], d_in[5], d_in[6],
                                                      c_cur, packed, T16, d_out);
    bucket_min<<<NB, 256, 0, stream>>>(c_cur, packed, T16, d_in[0], d_out);
}